// Round 8
// baseline (199.571 us; speedup 1.0000x reference)
//
#include <hip/hip_runtime.h>
#include <math.h>

#define NBINS 10
#define NB    32
#define HH    512
#define WW    512
#define HC    64
#define WC    64
#define NBR   63
#define NBC   63
#define EPS2F 1e-10f      // EPS^2, EPS=1e-5

// ---------------------------------------------------------------------------
// K1: fused Sobel + binning + 8x8 mean pool + Q-partial
//   cell[n][bin][cy][cx] (f32), Q[cy][cx] += sum_b cell^2 (f32 atomics)
// Block = (cy, n): 256 threads / 4 waves, 4 threads per cell.
// Histogram: per-cell LDS float atomics (ds_add_f32) instead of a
// runtime-indexed per-thread register array (which compiled to a ~60-instr
// cmp/cndmask chain per pixel).
// Bin decision numerics BYTE-IDENTICAL to passing rounds 3-6:
//   exact cross-product sector finder, guard band 3.2e-5*mag, fallback to
//   (float)atan2(double,double) f32-emulation. Fast path: cem=(flm+1)%10
//   always (exact-integer pb lies inside the guard band -> fallback).
// ---------------------------------------------------------------------------
__global__ __launch_bounds__(256) void k_cellhist(const float* __restrict__ img,
                                                  float* __restrict__ cell,
                                                  float* __restrict__ Q) {
    const int cy = blockIdx.x;   // 0..63
    const int n  = blockIdx.y;   // 0..31
    const int t  = threadIdx.x;  // 0..255

    __shared__ float lds[10][516];
    __shared__ float chist[64][NBINS];

    const float* im = img + (size_t)n * HH * WW;
    const int gy0 = cy * 8 - 1;
    for (int idx = t; idx < 10 * 514; idx += 256) {
        int r  = idx / 514;
        int c  = idx - r * 514;          // lds col 0..513, img col = c-1
        int gr = gy0 + r, gc = c - 1;
        float v = 0.0f;
        if ((unsigned)gr < HH && (unsigned)gc < WW) v = im[gr * WW + gc];
        lds[r][c] = v;
    }
    for (int idx = t; idx < 64 * NBINS; idx += 256)
        ((float*)chist)[idx] = 0.0f;
    __syncthreads();

    const float pi32 = (float)M_PI;          // 0x40490FDB
    // sin/cos(k*pi/10), k=1..4
    const float S1 = 0.30901699f, C1 = 0.95105652f;
    const float S2 = 0.58778525f, C2 = 0.80901699f;
    const float S3 = 0.80901699f, C3 = 0.58778525f;
    const float S4 = 0.95105652f, C4 = 0.30901699f;

    const int cc   = t >> 2;                 // cell 0..63
    const int sub  = t & 3;
    const int r0   = 1 + 2 * sub;            // strip pixel rows r0, r0+1
    const int stag = 2 * ((t >> 4) & 3) + sub;

    for (int ry = 0; ry < 2; ++ry) {
        const int row = r0 + ry;
        for (int k = 0; k < 8; ++k) {
            const int px  = (k + stag) & 7;
            const int col = cc * 8 + px + 1;
            float a  = lds[row - 1][col - 1];
            float b  = lds[row - 1][col    ];
            float c  = lds[row - 1][col + 1];
            float d  = lds[row    ][col - 1];
            float f  = lds[row    ][col + 1];
            float g  = lds[row + 1][col - 1];
            float h  = lds[row + 1][col    ];
            float i2 = lds[row + 1][col + 1];
            // identical accumulation order to the passing round-3 kernel
            float gA = a;
            gA = gA - c;
            gA = gA + 2.0f * d;
            gA = gA - 2.0f * f;
            gA = gA + g;
            gA = gA - i2;
            float gB = a;
            gB = gB + 2.0f * b;
            gB = gB + c;
            gB = gB - g;
            gB = gB - 2.0f * h;
            gB = gB - i2;

            float mag = sqrtf(gA * gA + gB * gB);

            // exact sector via cross products (quadrant-reduced)
            float y = fabsf(gA), x = fabsf(gB);
            float cr1 = fmaf(y, C1, -(x * S1));
            float cr2 = fmaf(y, C2, -(x * S2));
            float cr3 = fmaf(y, C3, -(x * S3));
            float cr4 = fmaf(y, C4, -(x * S4));
            int idx = (cr1 > 0.0f) + (cr2 > 0.0f) + (cr3 > 0.0f) + (cr4 > 0.0f);
            float minc = fminf(fminf(y, x),
                               fminf(fminf(fabsf(cr1), fabsf(cr2)),
                                     fminf(fabsf(cr3), fabsf(cr4))));
            int flm, cem;
            if (minc > 3.2e-5f * mag) {
                bool same = (gA >= 0.0f) == (gB >= 0.0f);
                flm = same ? idx : 9 - idx;
                cem = flm + 1; if (cem == NBINS) cem = 0;   // == (flm+1)%10 here
            } else {
                // exact f32-emulation fallback (round-3 verified, bit-identical)
                float phase = (float)atan2((double)gA, (double)gB);
                float pb = phase / pi32;
                pb = pb * 10.0f;
                int fl = (int)floorf(pb);
                int ce = (int)ceilf(pb);
                flm = fl % NBINS; if (flm < 0) flm += NBINS;   // Python %
                cem = ce % NBINS; if (cem < 0) cem += NBINS;
            }
            atomicAdd(&chist[cc][flm], mag);
            atomicAdd(&chist[cc][cem], 1.0f - mag);
        }
    }
    __syncthreads();

    // write cell: wave w covers bins {w, w+4, w+8}; lanes 0..63 = cx (coalesced)
    const int lane = t & 63, w = t >> 6;
#pragma unroll
    for (int bb = w; bb < NBINS; bb += 4)
        cell[(((size_t)n * NBINS + bb) * HC + cy) * WC + lane] =
            chist[lane][bb] * 0.015625f;

    // fused Q-partial: one lane per cell
    if (t < 64) {
        float q = 0.0f;
#pragma unroll
        for (int bb = 0; bb < NBINS; ++bb) {
            float cv = chist[t][bb] * 0.015625f;
            q = fmaf(cv, cv, q);
        }
        atomicAdd(&Q[cy * WC + t], q);
    }
}

// ---------------------------------------------------------------------------
// K2: block per (i,j): s2 = sum over 1280 of min(cell*inv1,0.2)^2 via
// LDS tree reduce; writes inv1[ij], inv2[ij]. No global atomics.
// ---------------------------------------------------------------------------
__global__ __launch_bounds__(256) void k_norm(const float* __restrict__ cell,
                                              const float* __restrict__ Q,
                                              float* __restrict__ inv1,
                                              float* __restrict__ inv2) {
    const int ij = blockIdx.x;          // 0..3968
    const int i  = ij / NBC, j = ij - i * NBC;
    const int t  = threadIdx.x;

    float s = Q[i * WC + j] + Q[i * WC + j + 1] +
              Q[(i + 1) * WC + j] + Q[(i + 1) * WC + j + 1];
    float w = 1.0f / sqrtf(s + EPS2F);

    float acc = 0.0f;
    // 320 slices (n*bin), thread t handles slices t, t+256
    for (int s0 = t; s0 < NB * NBINS; s0 += 256) {
        const float* base = cell + ((size_t)s0 * HC + i) * WC + j;
        float v00 = base[0],  v01 = base[1];
        float v10 = base[WC], v11 = base[WC + 1];
        v00 = fminf(v00 * w, 0.2f); acc = fmaf(v00, v00, acc);
        v01 = fminf(v01 * w, 0.2f); acc = fmaf(v01, v01, acc);
        v10 = fminf(v10 * w, 0.2f); acc = fmaf(v10, v10, acc);
        v11 = fminf(v11 * w, 0.2f); acc = fmaf(v11, v11, acc);
    }
    // wave reduce then LDS reduce across 4 waves
#pragma unroll
    for (int o = 1; o < 64; o <<= 1) acc += __shfl_xor(acc, o);
    __shared__ float red[4];
    if ((t & 63) == 0) red[t >> 6] = acc;
    __syncthreads();
    if (t == 0) {
        float s2 = red[0] + red[1] + red[2] + red[3];
        inv1[ij] = w;
        inv2[ij] = 1.0f / sqrtf(s2 + EPS2F);
    }
}

// ---------------------------------------------------------------------------
// K3: final write out[n][bin][di][dj][i][j] — pure streaming f32
// ---------------------------------------------------------------------------
__global__ void k_out(const float* __restrict__ cell,
                      const float* __restrict__ inv1,
                      const float* __restrict__ inv2,
                      float* __restrict__ out) {
    int idx = blockIdx.x * blockDim.x + threadIdx.x;
    const int total = NB * NBINS * 2 * 2 * NBR * NBC;
    if (idx >= total) return;
    int ij  = idx % (NBR * NBC);
    int tmp = idx / (NBR * NBC);
    int j   = ij % NBC;
    int i   = ij / NBC;
    int dj  = tmp % 2;   tmp /= 2;
    int di  = tmp % 2;   tmp /= 2;
    int b   = tmp % NBINS;
    int n   = tmp / NBINS;
    float v = cell[(((size_t)n * NBINS + b) * HC + i + di) * WC + j + dj] * inv1[ij];
    v = fminf(v, 0.2f);
    out[idx] = v * inv2[ij];
}

// ---------------------------------------------------------------------------
extern "C" void kernel_launch(void* const* d_in, const int* in_sizes, int n_in,
                              void* d_out, int out_size, void* d_ws, size_t ws_size,
                              hipStream_t stream) {
    const float* img = (const float*)d_in[0];   // (32,1,512,512) f32
    float* out = (float*)d_out;

    float* cell = (float*)d_ws;                           // 32*10*64*64
    float* Q    = cell + (size_t)NB * NBINS * HC * WC;    // 64*64
    float* inv1 = Q + HC * WC;                            // 63*63
    float* inv2 = inv1 + NBR * NBC;                       // 63*63

    hipMemsetAsync(Q, 0, (size_t)(HC * WC) * sizeof(float), stream);
    hipLaunchKernelGGL(k_cellhist, dim3(HC, NB), dim3(256), 0, stream, img, cell, Q);
    hipLaunchKernelGGL(k_norm, dim3(NBR * NBC), dim3(256), 0, stream,
                       cell, Q, inv1, inv2);
    const int total = NB * NBINS * 2 * 2 * NBR * NBC;
    hipLaunchKernelGGL(k_out, dim3((total + 255) / 256), dim3(256), 0, stream,
                       cell, inv1, inv2, out);
}

// Round 9
// 194.756 us; speedup vs baseline: 1.0247x; 1.0247x over previous
//
#include <hip/hip_runtime.h>
#include <math.h>

#define NBINS 10
#define NB    32
#define HH    512
#define WW    512
#define HC    64
#define WC    64
#define NBR   63
#define NBC   63
#define EPS2F 1e-10f      // EPS^2, EPS=1e-5
#define PHS   13          // private-hist stride: gcd(13,32)=1 -> conflict-free

// ---------------------------------------------------------------------------
// K1: fused Sobel + binning + 8x8 mean pool + Q-partial
// Block = (cy, n): 256 threads / 4 waves, 4 threads per cell (2 px-rows each).
// - Window registers R[4][10]: 40 static-offset ds_read_b32 per thread
//   (was 128 dynamically addressed); conv consumes same values, same order
//   -> bit-identical to passing rounds.
// - Histogram: PER-THREAD private LDS hist + ds_add_f32 (atomicAdd on LDS).
//   slot = t*13 + bin: zero same-address collisions across lanes, stride 13
//   covers all 32 banks (<=2 lanes/bank = free). Replaces the ~55-instr/px
//   cndmask select chain. (Round-8's per-CELL atomics serialized; private
//   slots cannot.)
// Bin decision numerics BYTE-IDENTICAL to passing rounds 3-8:
//   exact cross-product sector finder, guard band 3.2e-5*mag, fallback to
//   (float)atan2(double,double) f32-emulation; fast path cem=(flm+1)%10.
// ---------------------------------------------------------------------------
__global__ __launch_bounds__(256) void k_cellhist(const float* __restrict__ img,
                                                  float* __restrict__ cell,
                                                  float* __restrict__ Q) {
    const int cy = blockIdx.x;   // 0..63
    const int n  = blockIdx.y;   // 0..31
    const int t  = threadIdx.x;  // 0..255

    __shared__ float lds[10][516];
    __shared__ float ph[256 * PHS];

    const float* im = img + (size_t)n * HH * WW;
    const int gy0 = cy * 8 - 1;
    for (int idx = t; idx < 10 * 514; idx += 256) {
        int r  = idx / 514;
        int c  = idx - r * 514;          // lds col 0..513, img col = c-1
        int gr = gy0 + r, gc = c - 1;
        float v = 0.0f;
        if ((unsigned)gr < HH && (unsigned)gc < WW) v = im[gr * WW + gc];
        lds[r][c] = v;
    }
#pragma unroll
    for (int b = 0; b < NBINS; ++b) ph[t * PHS + b] = 0.0f;
    __syncthreads();

    const float pi32 = (float)M_PI;          // 0x40490FDB
    // sin/cos(k*pi/10), k=1..4
    const float S1 = 0.30901699f, C1 = 0.95105652f;
    const float S2 = 0.58778525f, C2 = 0.80901699f;
    const float S3 = 0.80901699f, C3 = 0.58778525f;
    const float S4 = 0.95105652f, C4 = 0.30901699f;

    const int cc  = t >> 2;                  // cell 0..63
    const int sub = t & 3;
    const int r0  = 1 + 2 * sub;             // pixel rows r0, r0+1 of the strip

    // window: rows r0-1 .. r0+2, lds cols cc*8 .. cc*8+9 (static offsets)
    float R[4][10];
#pragma unroll
    for (int r = 0; r < 4; ++r)
#pragma unroll
        for (int q = 0; q < 10; ++q)
            R[r][q] = lds[r0 - 1 + r][cc * 8 + q];

    float* myph = &ph[t * PHS];

#pragma unroll
    for (int ry = 0; ry < 2; ++ry) {
#pragma unroll
        for (int k = 0; k < 8; ++k) {
            float a  = R[ry    ][k    ];
            float b  = R[ry    ][k + 1];
            float c  = R[ry    ][k + 2];
            float d  = R[ry + 1][k    ];
            float f  = R[ry + 1][k + 2];
            float g  = R[ry + 2][k    ];
            float h  = R[ry + 2][k + 1];
            float i2 = R[ry + 2][k + 2];
            // identical accumulation order to the passing round-3 kernel
            float gA = a;
            gA = gA - c;
            gA = gA + 2.0f * d;
            gA = gA - 2.0f * f;
            gA = gA + g;
            gA = gA - i2;
            float gB = a;
            gB = gB + 2.0f * b;
            gB = gB + c;
            gB = gB - g;
            gB = gB - 2.0f * h;
            gB = gB - i2;

            float mag = sqrtf(gA * gA + gB * gB);

            // exact sector via cross products (quadrant-reduced)
            float y = fabsf(gA), x = fabsf(gB);
            float cr1 = fmaf(y, C1, -(x * S1));
            float cr2 = fmaf(y, C2, -(x * S2));
            float cr3 = fmaf(y, C3, -(x * S3));
            float cr4 = fmaf(y, C4, -(x * S4));
            int idx = (cr1 > 0.0f) + (cr2 > 0.0f) + (cr3 > 0.0f) + (cr4 > 0.0f);
            float minc = fminf(fminf(y, x),
                               fminf(fminf(fabsf(cr1), fabsf(cr2)),
                                     fminf(fabsf(cr3), fabsf(cr4))));
            int flm, cem;
            if (minc > 3.2e-5f * mag) {
                bool same = (gA >= 0.0f) == (gB >= 0.0f);
                flm = same ? idx : 9 - idx;
                cem = flm + 1; if (cem == NBINS) cem = 0;   // == (flm+1)%10 here
            } else {
                // exact f32-emulation fallback (round-3 verified, bit-identical)
                float phase = (float)atan2((double)gA, (double)gB);
                float pb = phase / pi32;
                pb = pb * 10.0f;
                int fl = (int)floorf(pb);
                int ce = (int)ceilf(pb);
                flm = fl % NBINS; if (flm < 0) flm += NBINS;   // Python %
                cem = ce % NBINS; if (cem < 0) cem += NBINS;
            }
            atomicAdd(&myph[flm], mag);          // ds_add_f32, private slot
            atomicAdd(&myph[cem], 1.0f - mag);
        }
    }
    __syncthreads();

    // merge 4 sub-partials per cell; one wave writes cell + Q
    if (t < 64) {
        const int L = t;                      // cell col cx = L
        float q = 0.0f;
        size_t base = ((size_t)n * NBINS) * HC * WC + (size_t)cy * WC + L;
#pragma unroll
        for (int bb = 0; bb < NBINS; ++bb) {
            float v = ph[(4 * L + 0) * PHS + bb] + ph[(4 * L + 1) * PHS + bb] +
                      ph[(4 * L + 2) * PHS + bb] + ph[(4 * L + 3) * PHS + bb];
            v *= 0.015625f;
            cell[base + (size_t)bb * HC * WC] = v;   // lanes coalesced in L
            q = fmaf(v, v, q);
        }
        atomicAdd(&Q[cy * WC + L], q);
    }
}

// ---------------------------------------------------------------------------
// K2: block per (i,j): s2 = sum over 1280 of min(cell*inv1,0.2)^2 via
// LDS tree reduce; writes inv1[ij], inv2[ij]. No global atomics.
// ---------------------------------------------------------------------------
__global__ __launch_bounds__(256) void k_norm(const float* __restrict__ cell,
                                              const float* __restrict__ Q,
                                              float* __restrict__ inv1,
                                              float* __restrict__ inv2) {
    const int ij = blockIdx.x;          // 0..3968
    const int i  = ij / NBC, j = ij - i * NBC;
    const int t  = threadIdx.x;

    float s = Q[i * WC + j] + Q[i * WC + j + 1] +
              Q[(i + 1) * WC + j] + Q[(i + 1) * WC + j + 1];
    float w = 1.0f / sqrtf(s + EPS2F);

    float acc = 0.0f;
    for (int s0 = t; s0 < NB * NBINS; s0 += 256) {
        const float* base = cell + ((size_t)s0 * HC + i) * WC + j;
        float v00 = base[0],  v01 = base[1];
        float v10 = base[WC], v11 = base[WC + 1];
        v00 = fminf(v00 * w, 0.2f); acc = fmaf(v00, v00, acc);
        v01 = fminf(v01 * w, 0.2f); acc = fmaf(v01, v01, acc);
        v10 = fminf(v10 * w, 0.2f); acc = fmaf(v10, v10, acc);
        v11 = fminf(v11 * w, 0.2f); acc = fmaf(v11, v11, acc);
    }
#pragma unroll
    for (int o = 1; o < 64; o <<= 1) acc += __shfl_xor(acc, o);
    __shared__ float red[4];
    if ((t & 63) == 0) red[t >> 6] = acc;
    __syncthreads();
    if (t == 0) {
        float s2 = red[0] + red[1] + red[2] + red[3];
        inv1[ij] = w;
        inv2[ij] = 1.0f / sqrtf(s2 + EPS2F);
    }
}

// ---------------------------------------------------------------------------
// K3: final write out[n][bin][di][dj][i][j] — pure streaming f32
// ---------------------------------------------------------------------------
__global__ void k_out(const float* __restrict__ cell,
                      const float* __restrict__ inv1,
                      const float* __restrict__ inv2,
                      float* __restrict__ out) {
    int idx = blockIdx.x * blockDim.x + threadIdx.x;
    const int total = NB * NBINS * 2 * 2 * NBR * NBC;
    if (idx >= total) return;
    int ij  = idx % (NBR * NBC);
    int tmp = idx / (NBR * NBC);
    int j   = ij % NBC;
    int i   = ij / NBC;
    int dj  = tmp % 2;   tmp /= 2;
    int di  = tmp % 2;   tmp /= 2;
    int b   = tmp % NBINS;
    int n   = tmp / NBINS;
    float v = cell[(((size_t)n * NBINS + b) * HC + i + di) * WC + j + dj] * inv1[ij];
    v = fminf(v, 0.2f);
    out[idx] = v * inv2[ij];
}

// ---------------------------------------------------------------------------
extern "C" void kernel_launch(void* const* d_in, const int* in_sizes, int n_in,
                              void* d_out, int out_size, void* d_ws, size_t ws_size,
                              hipStream_t stream) {
    const float* img = (const float*)d_in[0];   // (32,1,512,512) f32
    float* out = (float*)d_out;

    float* cell = (float*)d_ws;                           // 32*10*64*64
    float* Q    = cell + (size_t)NB * NBINS * HC * WC;    // 64*64
    float* inv1 = Q + HC * WC;                            // 63*63
    float* inv2 = inv1 + NBR * NBC;                       // 63*63

    hipMemsetAsync(Q, 0, (size_t)(HC * WC) * sizeof(float), stream);
    hipLaunchKernelGGL(k_cellhist, dim3(HC, NB), dim3(256), 0, stream, img, cell, Q);
    hipLaunchKernelGGL(k_norm, dim3(NBR * NBC), dim3(256), 0, stream,
                       cell, Q, inv1, inv2);
    const int total = NB * NBINS * 2 * 2 * NBR * NBC;
    hipLaunchKernelGGL(k_out, dim3((total + 255) / 256), dim3(256), 0, stream,
                       cell, inv1, inv2, out);
}

// Round 10
// 130.114 us; speedup vs baseline: 1.5338x; 1.4968x over previous
//
#include <hip/hip_runtime.h>
#include <math.h>

#define NBINS 10
#define NB    32
#define HH    512
#define WW    512
#define HC    64
#define WC    64
#define NBR   63
#define NBC   63
#define EPS2F 1e-10f      // EPS^2, EPS=1e-5

// ---------------------------------------------------------------------------
// K1: fused Sobel + binning + 8x8 mean pool + Q-partial
// Block = (cy, n): 256 threads / 4 waves, 4 threads per cell (2 px-rows each).
// - Window registers R[4][10] loaded via ds_read_b128/b64 (12 wide DS reads
//   per thread; row stride 516 f32 = 2064 B is 16B-aligned, cc*8 floats =
//   32 B): replaces 128 dynamically-addressed ds_read_b32 + per-pixel
//   address arithmetic (round-6's hidden ~150 instr/px).
// - Histogram in VGPRs (cndmask chain). Rounds 8/9 proved LDS atomics
//   (per-cell AND private-slot) serialize on the shared DS pipe: 113/107 us,
//   VALUBusy 18%. Register scatter: 50 us, VALUBusy 65%.
// - mag via raw v_sqrt_f32 (continuous-only; bins never read mag, guard has
//   25x margin vs 2e-7 rel err).
// Bin decision numerics BYTE-IDENTICAL to passing rounds 3-9:
//   exact cross-product sector finder, guard band 3.2e-5*mag, fallback to
//   (float)atan2(double,double) f32-emulation; fast path cem=(flm+1)%10.
// ---------------------------------------------------------------------------
__global__ __launch_bounds__(256) void k_cellhist(const float* __restrict__ img,
                                                  float* __restrict__ cell,
                                                  float* __restrict__ Q) {
    const int cy = blockIdx.x;   // 0..63
    const int n  = blockIdx.y;   // 0..31
    const int t  = threadIdx.x;  // 0..255

    __shared__ float lds[10][516];

    const float* im = img + (size_t)n * HH * WW;
    const int gy0 = cy * 8 - 1;
    for (int idx = t; idx < 10 * 514; idx += 256) {
        int r  = idx / 514;
        int c  = idx - r * 514;          // lds col 0..513, img col = c-1
        int gr = gy0 + r, gc = c - 1;
        float v = 0.0f;
        if ((unsigned)gr < HH && (unsigned)gc < WW) v = im[gr * WW + gc];
        lds[r][c] = v;
    }
    __syncthreads();

    const float pi32 = (float)M_PI;          // 0x40490FDB
    // sin/cos(k*pi/10), k=1..4
    const float S1 = 0.30901699f, C1 = 0.95105652f;
    const float S2 = 0.58778525f, C2 = 0.80901699f;
    const float S3 = 0.80901699f, C3 = 0.58778525f;
    const float S4 = 0.95105652f, C4 = 0.30901699f;

    const int cc  = t >> 2;                  // cell 0..63
    const int sub = t & 3;
    const int r0  = 1 + 2 * sub;             // pixel rows r0, r0+1 of the strip

    // window registers: rows r0-1..r0+2, cols cc*8 .. cc*8+9 (wide DS reads)
    float R[4][10];
#pragma unroll
    for (int r = 0; r < 4; ++r) {
        const float* rowp = &lds[r0 - 1 + r][cc * 8];
        float4 v0 = *(const float4*)(rowp);
        float4 v1 = *(const float4*)(rowp + 4);
        float2 v2 = *(const float2*)(rowp + 8);
        R[r][0] = v0.x; R[r][1] = v0.y; R[r][2] = v0.z; R[r][3] = v0.w;
        R[r][4] = v1.x; R[r][5] = v1.y; R[r][6] = v1.z; R[r][7] = v1.w;
        R[r][8] = v2.x; R[r][9] = v2.y;
    }

    float hist[NBINS];
#pragma unroll
    for (int b = 0; b < NBINS; ++b) hist[b] = 0.0f;

#pragma unroll
    for (int ry = 0; ry < 2; ++ry) {
#pragma unroll
        for (int k = 0; k < 8; ++k) {
            float a  = R[ry    ][k    ];
            float b  = R[ry    ][k + 1];
            float c  = R[ry    ][k + 2];
            float d  = R[ry + 1][k    ];
            float f  = R[ry + 1][k + 2];
            float g  = R[ry + 2][k    ];
            float h  = R[ry + 2][k + 1];
            float i2 = R[ry + 2][k + 2];
            // identical accumulation order to the passing round-3 kernel
            float gA = a;
            gA = gA - c;
            gA = gA + 2.0f * d;
            gA = gA - 2.0f * f;
            gA = gA + g;
            gA = gA - i2;
            float gB = a;
            gB = gB + 2.0f * b;
            gB = gB + c;
            gB = gB - g;
            gB = gB - 2.0f * h;
            gB = gB - i2;

            float mag = __builtin_amdgcn_sqrtf(gA * gA + gB * gB);

            // exact sector via cross products (quadrant-reduced)
            float y = fabsf(gA), x = fabsf(gB);
            float cr1 = fmaf(y, C1, -(x * S1));
            float cr2 = fmaf(y, C2, -(x * S2));
            float cr3 = fmaf(y, C3, -(x * S3));
            float cr4 = fmaf(y, C4, -(x * S4));
            int idx = (cr1 > 0.0f) + (cr2 > 0.0f) + (cr3 > 0.0f) + (cr4 > 0.0f);
            float minc = fminf(fminf(y, x),
                               fminf(fminf(fabsf(cr1), fabsf(cr2)),
                                     fminf(fabsf(cr3), fabsf(cr4))));
            int flm, cem;
            if (minc > 3.2e-5f * mag) {
                bool same = (gA >= 0.0f) == (gB >= 0.0f);
                flm = same ? idx : 9 - idx;
                cem = flm + 1; if (cem == NBINS) cem = 0;   // == (flm+1)%10 here
            } else {
                // exact f32-emulation fallback (round-3 verified, bit-identical)
                float phase = (float)atan2((double)gA, (double)gB);
                float pb = phase / pi32;
                pb = pb * 10.0f;
                int fl = (int)floorf(pb);
                int ce = (int)ceilf(pb);
                flm = fl % NBINS; if (flm < 0) flm += NBINS;   // Python %
                cem = ce % NBINS; if (cem < 0) cem += NBINS;
            }
            hist[flm] += mag;
            hist[cem] += 1.0f - mag;
        }
    }

    // merge the 4 per-thread partials of each cell (lanes 4c..4c+3)
#pragma unroll
    for (int b = 0; b < NBINS; ++b) {
        hist[b] += __shfl_xor(hist[b], 1);
        hist[b] += __shfl_xor(hist[b], 2);
    }

    // write cell (each sub writes bins with (b&3)==sub, coalesced in cc)
#pragma unroll
    for (int bb = 0; bb < NBINS; ++bb) {
        if ((bb & 3) == sub)
            cell[(((size_t)n * NBINS + bb) * HC + cy) * WC + cc] = hist[bb] * 0.015625f;
    }
    // fused Q-partial: sub==0 lane of each cell adds sum_b cell^2
    if (sub == 0) {
        float q = 0.0f;
#pragma unroll
        for (int bb = 0; bb < NBINS; ++bb) {
            float cv = hist[bb] * 0.015625f;
            q = fmaf(cv, cv, q);
        }
        atomicAdd(&Q[cy * WC + cc], q);
    }
}

// ---------------------------------------------------------------------------
// K2: s2[i][j] = sum over (n,bin,di,dj) of min(cell*inv1, 0.2)^2   (f32)
// Block = (i, chunk): 256 threads = 64 j-lanes x 4 subs; 10 nb-groups each.
// (round-6 verbatim — passed)
// ---------------------------------------------------------------------------
__global__ __launch_bounds__(256) void k_s2(const float* __restrict__ cell,
                                            const float* __restrict__ Q,
                                            float* __restrict__ s2) {
    const int i     = blockIdx.x;   // 0..62
    const int chunk = blockIdx.y;   // 0..7
    const int t     = threadIdx.x;
    const int j     = t & 63;
    const int sub   = t >> 6;       // 0..3
    if (j >= NBC) return;
    float s = Q[i * WC + j] + Q[i * WC + j + 1] +
              Q[(i + 1) * WC + j] + Q[(i + 1) * WC + j + 1];
    float w = 1.0f / sqrtf(s + EPS2F);
    float acc = 0.0f;
    const int nb0 = (chunk * 4 + sub) * 10;     // 32 slices x 10 nb
    for (int nb = nb0; nb < nb0 + 10; ++nb) {
        const float* base = cell + ((size_t)nb * HC + i) * WC + j;
        float v00 = base[0], v01 = base[1];
        float v10 = base[WC], v11 = base[WC + 1];
        v00 = fminf(v00 * w, 0.2f); acc = fmaf(v00, v00, acc);
        v01 = fminf(v01 * w, 0.2f); acc = fmaf(v01, v01, acc);
        v10 = fminf(v10 * w, 0.2f); acc = fmaf(v10, v10, acc);
        v11 = fminf(v11 * w, 0.2f); acc = fmaf(v11, v11, acc);
    }
    atomicAdd(&s2[i * NBC + j], acc);
}

// ---------------------------------------------------------------------------
// K3: inv1[ij] = 1/sqrt(s+eps^2), inv2[ij] = 1/sqrt(s2+eps^2)   (3969 elems)
// ---------------------------------------------------------------------------
__global__ void k_inv(const float* __restrict__ Q, const float* __restrict__ s2,
                      float* __restrict__ inv1, float* __restrict__ inv2) {
    int idx = blockIdx.x * blockDim.x + threadIdx.x;
    if (idx >= NBR * NBC) return;
    int i = idx / NBC, j = idx - i * NBC;
    float s = Q[i * WC + j] + Q[i * WC + j + 1] +
              Q[(i + 1) * WC + j] + Q[(i + 1) * WC + j + 1];
    inv1[idx] = 1.0f / sqrtf(s + EPS2F);
    inv2[idx] = 1.0f / sqrtf(s2[idx] + EPS2F);
}

// ---------------------------------------------------------------------------
// K4: final write out[n][bin][di][dj][i][j] — pure streaming f32
// ---------------------------------------------------------------------------
__global__ void k_out(const float* __restrict__ cell,
                      const float* __restrict__ inv1,
                      const float* __restrict__ inv2,
                      float* __restrict__ out) {
    int idx = blockIdx.x * blockDim.x + threadIdx.x;
    const int total = NB * NBINS * 2 * 2 * NBR * NBC;
    if (idx >= total) return;
    int ij  = idx % (NBR * NBC);
    int tmp = idx / (NBR * NBC);
    int j   = ij % NBC;
    int i   = ij / NBC;
    int dj  = tmp % 2;   tmp /= 2;
    int di  = tmp % 2;   tmp /= 2;
    int b   = tmp % NBINS;
    int n   = tmp / NBINS;
    float v = cell[(((size_t)n * NBINS + b) * HC + i + di) * WC + j + dj] * inv1[ij];
    v = fminf(v, 0.2f);
    out[idx] = v * inv2[ij];
}

// ---------------------------------------------------------------------------
extern "C" void kernel_launch(void* const* d_in, const int* in_sizes, int n_in,
                              void* d_out, int out_size, void* d_ws, size_t ws_size,
                              hipStream_t stream) {
    const float* img = (const float*)d_in[0];   // (32,1,512,512) f32
    float* out = (float*)d_out;

    float* cell = (float*)d_ws;                           // 32*10*64*64
    float* Q    = cell + (size_t)NB * NBINS * HC * WC;    // 64*64
    float* s2   = Q + HC * WC;                            // 63*63
    float* inv1 = s2 + NBR * NBC;                         // 63*63
    float* inv2 = inv1 + NBR * NBC;                       // 63*63

    // zero the two atomic accumulators (contiguous) in one async memset
    hipMemsetAsync(Q, 0, (size_t)(HC * WC + NBR * NBC) * sizeof(float), stream);
    hipLaunchKernelGGL(k_cellhist, dim3(HC, NB), dim3(256), 0, stream, img, cell, Q);
    hipLaunchKernelGGL(k_s2, dim3(NBR, 8), dim3(256), 0, stream, cell, Q, s2);
    hipLaunchKernelGGL(k_inv, dim3(16), dim3(256), 0, stream, Q, s2, inv1, inv2);
    const int total = NB * NBINS * 2 * 2 * NBR * NBC;
    hipLaunchKernelGGL(k_out, dim3((total + 255) / 256), dim3(256), 0, stream,
                       cell, inv1, inv2, out);
}